// Round 3
// baseline (7872.313 us; speedup 1.0000x reference)
//
#include <hip/hip_runtime.h>

// ============================================================================
// GeneratorBilinear: fused PGA(3,0,1) bilinear block on MI355X (gfx950).
// Round 6: round-5 structure, workspace reverted to the known-good 248,832 B
// [9][96][48]/[9][48][48] weight planes (round-5's 359 KB packing is the one
// plausible container-killer: possible d_ws overflow).
//
//   stage0 : x tile -> LDS (Gs overlay), coalesced float4
//   cols   : xr[48] (+xr2[48] on e0 waves) <- LDS columns, ONCE per thread
//   stage1a: h[o in 0:48)  -> Hs   (thread = (p,blade,oh), streams 24 o's)
//   stage2a: gp  (free waves only) reads Hs, writes Gs rows 0..23
//   stage1b: h[o in 48:96) -> Hs (overwrite)
//   stage2b: join (free waves only) -> Gs rows 24..47 (x ref pseudoscalar)
//   stage3 : out = equi_linear(G, w_next), gr[48] columns in regs -> Hs(outS)
//   stage4 : coalesced store
//
// equi_linear decomposition (verified against reference basis construction):
//   out[o,k] = sum_i w[o,i,grade(k)] * x[i,k]
//            + (e0 in k) * sum_i w[o,i,4+grade(k)] * x[i, k\e0]
// (all e0-multiplication basis signs are +1)
// ============================================================================

// ---------------- compile-time PGA tables (mirror reference _mul) -----------
constexpr unsigned char BB[16] = {
  0x0, 0x1, 0x2, 0x4, 0x8,            // (), e0, e1, e2, e3
  0x3, 0x5, 0x9, 0x6, 0xA, 0xC,       // e01,e02,e03,e12,e13,e23
  0x7, 0xB, 0xD, 0xE,                 // e012,e013,e023,e123
  0xF                                 // e0123
};
constexpr int popc4(unsigned x){ return (x&1)+((x>>1)&1)+((x>>2)&1)+((x>>3)&1); }
constexpr int idx_of(unsigned bits){
  int r = 0;
  for (int i = 0; i < 16; ++i) if (BB[i] == bits) r = i;
  return r;
}
constexpr int reorder_sign(unsigned a, unsigned b){
  int sw = 0;
  for (int g = 0; g < 4; ++g) if (b & (1u<<g)) sw += popc4(a >> (g+1));
  return (sw & 1) ? -1 : 1;
}
struct Tab { signed char s[16][16]; signed char k[16][16]; };
constexpr Tab make_gp(){
  Tab t{};
  for (int i = 0; i < 16; ++i)
    for (int j = 0; j < 16; ++j){
      unsigned a = BB[i], b = BB[j];
      if ((a & b) & 1u) { t.s[i][j] = 0; t.k[i][j] = 0; }    // e0^2 = 0
      else { t.s[i][j] = (signed char)reorder_sign(a,b);
             t.k[i][j] = (signed char)idx_of(a ^ b); }
    }
  return t;
}
constexpr int d_idx(int i){ return idx_of(0xFu ^ BB[i]); }
constexpr int d_sgn(int i){ return reorder_sign(BB[i], 0xFu ^ BB[i]); }
constexpr Tab make_join(){
  Tab t{};
  for (int a = 0; a < 16; ++a)
    for (int b = 0; b < 16; ++b){
      int da = d_idx(a), db = d_idx(b);
      if (BB[da] & BB[db]) { t.s[a][b] = 0; t.k[a][b] = 0; }
      else {
        int ws = reorder_sign(BB[da], BB[db]);
        int m  = idx_of(BB[da] ^ BB[db]);
        int l  = idx_of(0xFu ^ BB[m]);
        t.s[a][b] = (signed char)(d_sgn(a) * d_sgn(b) * ws * d_sgn(l));
        t.k[a][b] = (signed char)l;
      }
    }
  return t;
}
constexpr Tab GPT = make_gp();
constexpr Tab JNT = make_join();

struct ITab { int v[16]; };
constexpr ITab make_grade(){ ITab t{}; for (int i=0;i<16;++i) t.v[i]=popc4(BB[i]); return t; }
constexpr ITab make_partner(){ ITab t{}; for (int i=0;i<16;++i) t.v[i]=idx_of(BB[i] & ~1u); return t; }
constexpr ITab GRD = make_grade();
constexpr ITab PRT = make_partner();
// slots 0..7 = e0-free blades (waves 0,2), slots 8..15 = e0 blades (waves 1,3)
constexpr int KPERM[16] = {0,2,3,4,8,9,10,14,  1,5,6,7,11,12,13,15};

// ---------------- sizes ------------------------------------------------------
#define NPTS   65536          // B*P = 64*1024
#define CIN    48
#define CH     96
#define COUT   48
#define PTS    8              // points per block
#define ROWF   772            // fp32 elems per point row in LDS (768 + 4 pad)

// ---------------- weight prep: fp32 [o][i][9] -> fp32 [9][o][i] (known-good) -
__global__ void prep_weights(const float* __restrict__ wb,
                             const float* __restrict__ wn,
                             float* __restrict__ W1, float* __restrict__ W2){
  int i = blockIdx.x * 256 + threadIdx.x;
  if (i < 9*CH*CIN){
    int b = i / (CH*CIN); int r = i % (CH*CIN); int o = r / CIN; int c = r % CIN;
    W1[i] = wb[(o*CIN + c)*9 + b];
  }
  if (i < 9*COUT*CIN){
    int b = i / (COUT*CIN); int r = i % (COUT*CIN); int o = r / CIN; int c = r % CIN;
    W2[i] = wn[(o*CIN + c)*9 + b];
  }
}

// ---------------- helpers ----------------------------------------------------
#define LD16(dst, base) { \
  float4 q0_ = *(const float4*)((base)+0);  float4 q1_ = *(const float4*)((base)+4); \
  float4 q2_ = *(const float4*)((base)+8);  float4 q3_ = *(const float4*)((base)+12); \
  dst[0]=q0_.x;  dst[1]=q0_.y;  dst[2]=q0_.z;  dst[3]=q0_.w; \
  dst[4]=q1_.x;  dst[5]=q1_.y;  dst[6]=q1_.z;  dst[7]=q1_.w; \
  dst[8]=q2_.x;  dst[9]=q2_.y;  dst[10]=q2_.z; dst[11]=q2_.w; \
  dst[12]=q3_.x; dst[13]=q3_.y; dst[14]=q3_.z; dst[15]=q3_.w; }

#define ST16(base, src) { \
  *(float4*)((base)+0)  = make_float4(src[0], src[1], src[2], src[3]); \
  *(float4*)((base)+4)  = make_float4(src[4], src[5], src[6], src[7]); \
  *(float4*)((base)+8)  = make_float4(src[8], src[9], src[10],src[11]); \
  *(float4*)((base)+12) = make_float4(src[12],src[13],src[14],src[15]); }

// stage 1: h columns for o in [HA*48 + oh*24, +24), written to local rows oh*24+j
// W1 planes: basis b at W1 + b*(CH*CIN); row o at +o*CIN.
#define DO_LIN1(HA) do { \
  const int ob_ = (HA)*48 + oh*24; \
  if (isfree){ \
    const float* wpl_ = W1 + g*(CH*CIN) + ob_*CIN; \
    _Pragma("unroll 2") \
    for (int j = 0; j < 24; ++j){ \
      const float* wr_ = wpl_ + j*CIN; \
      float a0=0.f,a1=0.f,a2=0.f,a3=0.f; \
      _Pragma("unroll") \
      for (int i = 0; i < 48; i += 4){ \
        float4 wv = *(const float4*)(wr_ + i); \
        a0 += wv.x*xr[i];   a1 += wv.y*xr[i+1]; \
        a2 += wv.z*xr[i+2]; a3 += wv.w*xr[i+3]; \
      } \
      Hs[p*ROWF + (oh*24+j)*16 + k] = (a0+a1)+(a2+a3); \
    } \
  } else { \
    const float* wplA_ = W1 + g*(CH*CIN) + ob_*CIN; \
    const float* wplB_ = W1 + (4+g)*(CH*CIN) + ob_*CIN; \
    _Pragma("unroll 1") \
    for (int j = 0; j < 24; ++j){ \
      const float* wrA_ = wplA_ + j*CIN; \
      const float* wrB_ = wplB_ + j*CIN; \
      float a0=0.f,a1=0.f,a2=0.f,a3=0.f; \
      _Pragma("unroll") \
      for (int i = 0; i < 48; i += 4){ \
        float4 wv  = *(const float4*)(wrA_ + i); \
        float4 wv2 = *(const float4*)(wrB_ + i); \
        a0 += wv.x*xr[i];     a1 += wv.y*xr[i+1]; \
        a2 += wv.z*xr[i+2];   a3 += wv.w*xr[i+3]; \
        a0 += wv2.x*xr2[i];   a1 += wv2.y*xr2[i+1]; \
        a2 += wv2.z*xr2[i+2]; a3 += wv2.w*xr2[i+3]; \
      } \
      Hs[p*ROWF + (oh*24+j)*16 + k] = (a0+a1)+(a2+a3); \
    } \
  } \
} while(0)

// stage 2: bilinear tasks on free waves only (192 tasks over 128 lanes).
// JOIN=0: gp from Hs (channels c, 24+c) -> Gs rows 0..23
// JOIN=1: join from Hs (channels 48+c, 72+c at local rows c, 24+c) -> rows 24..47
#define DO_BILIN(JOIN, RPS) do { \
  if (isfree){ \
    const int fid_ = oh*64 + s*8 + p; \
    for (int u_ = fid_; u_ < 192; u_ += 128){ \
      const int pp_ = u_ & 7, c_ = u_ >> 3; \
      const float* hb_ = Hs + pp_*ROWF + c_*16; \
      float A[16], Bv[16], oo[16]; \
      LD16(A, hb_); LD16(Bv, hb_ + 384); \
      _Pragma("unroll") for (int kk = 0; kk < 16; ++kk) oo[kk] = 0.f; \
      _Pragma("unroll") \
      for (int ii = 0; ii < 16; ++ii){ \
        _Pragma("unroll") \
        for (int jj = 0; jj < 16; ++jj){ \
          const int sg_ = (JOIN) ? (int)JNT.s[ii][jj] : (int)GPT.s[ii][jj]; \
          const int kk_ = (JOIN) ? (int)JNT.k[ii][jj] : (int)GPT.k[ii][jj]; \
          if (sg_ > 0)      oo[kk_] += A[ii]*Bv[jj]; \
          else if (sg_ < 0) oo[kk_] -= A[ii]*Bv[jj]; \
        } \
      } \
      if (JOIN){ _Pragma("unroll") for (int kk = 0; kk < 16; ++kk) oo[kk] *= (RPS); } \
      float* gw_ = Gs + pp_*ROWF + ((JOIN)*24 + c_)*16; \
      ST16(gw_, oo); \
    } \
  } \
} while(0)

// ---------------- fused main kernel ------------------------------------------
__global__ __launch_bounds__(256, 3)
void fused_bilinear(const float* __restrict__ x,     // [NPTS][48][16] fp32
                    const float* __restrict__ refp,  // [64][16] fp32
                    const float* __restrict__ W1,    // [9][96][48] fp32
                    const float* __restrict__ W2,    // [9][48][48] fp32
                    float* __restrict__ out){        // [NPTS][48][16] fp32
  __shared__ float Hs[PTS * ROWF];   // 24,704 B : h half-tile, later out staging
  __shared__ float Gs[PTS * ROWF];   // 24,704 B : x tile, then [gp;join] tile
                                     // total 49,408 B -> 3 blocks/CU

  const int t  = threadIdx.x;
  const long p0 = (long)blockIdx.x * PTS;

  const int p  = t & 7;              // point within tile
  const int s  = (t >> 3) & 15;      // blade slot
  const int oh = t >> 7;             // o-half within each 48-range
  const int k  = KPERM[s];
  const int g  = GRD.v[k];
  const bool isfree = (s < 8);       // wave-uniform (waves 0,2 free; 1,3 e0)

  // ---- stage 0: coalesced x tile -> Gs ----
  for (int c = t; c < PTS * 192; c += 256){
    int pp = c / 192, r = c % 192;
    ((float4*)(Gs + pp * ROWF))[r] = ((const float4*)(x + (p0 + pp) * 768))[r];
  }
  __syncthreads();

  // ---- x columns -> registers (once) ----
  float xr[48], xr2[48];
  #pragma unroll
  for (int i = 0; i < 48; ++i) xr[i] = Gs[p*ROWF + i*16 + k];
  if (!isfree){
    const int kp = PRT.v[k];
    #pragma unroll
    for (int i = 0; i < 48; ++i) xr2[i] = Gs[p*ROWF + i*16 + kp];
  }

  const float rps = refp[(int)(p0 >> 10) * 16 + 15];  // batch-uniform pseudoscalar

  // ---- stage 1a: h[0:48) ----
  DO_LIN1(0);
  __syncthreads();          // Hs ready; everyone's x column reads are done too

  // ---- stage 2a: geometric product -> Gs rows 0..23 (free waves) ----
  DO_BILIN(0, 0.f);
  __syncthreads();

  // ---- stage 1b: h[48:96) (overwrite Hs) ----
  DO_LIN1(1);
  __syncthreads();

  // ---- stage 2b: join -> Gs rows 24..47 (free waves) ----
  DO_BILIN(1, rps);
  __syncthreads();

  // ---- stage 3: out = equi_linear(G, w_next); columns in regs -> Hs(outS) ----
  float gr[48], gr2[48];
  #pragma unroll
  for (int c = 0; c < 48; ++c) gr[c] = Gs[p*ROWF + c*16 + k];
  if (!isfree){
    const int kp = PRT.v[k];
    #pragma unroll
    for (int c = 0; c < 48; ++c) gr2[c] = Gs[p*ROWF + c*16 + kp];
  }

  if (isfree){
    const float* wpl = W2 + g*(COUT*CIN);
    #pragma unroll 2
    for (int j = 0; j < 24; ++j){
      const int o = oh*24 + j;
      const float* wr_ = wpl + o*CIN;
      float a0=0.f,a1=0.f,a2=0.f,a3=0.f;
      #pragma unroll
      for (int c = 0; c < 48; c += 4){
        float4 wv = *(const float4*)(wr_ + c);
        a0 += wv.x*gr[c];   a1 += wv.y*gr[c+1];
        a2 += wv.z*gr[c+2]; a3 += wv.w*gr[c+3];
      }
      Hs[p*ROWF + o*16 + k] = (a0+a1)+(a2+a3);
    }
  } else {
    const float* wplA = W2 + g*(COUT*CIN);
    const float* wplB = W2 + (4+g)*(COUT*CIN);
    #pragma unroll 1
    for (int j = 0; j < 24; ++j){
      const int o = oh*24 + j;
      const float* wrA_ = wplA + o*CIN;
      const float* wrB_ = wplB + o*CIN;
      float a0=0.f,a1=0.f,a2=0.f,a3=0.f;
      #pragma unroll
      for (int c = 0; c < 48; c += 4){
        float4 wv  = *(const float4*)(wrA_ + c);
        float4 wv2 = *(const float4*)(wrB_ + c);
        a0 += wv.x*gr[c];     a1 += wv.y*gr[c+1];
        a2 += wv.z*gr[c+2];   a3 += wv.w*gr[c+3];
        a0 += wv2.x*gr2[c];   a1 += wv2.y*gr2[c+1];
        a2 += wv2.z*gr2[c+2]; a3 += wv2.w*gr2[c+3];
      }
      Hs[p*ROWF + o*16 + k] = (a0+a1)+(a2+a3);
    }
  }
  __syncthreads();

  // ---- stage 4: coalesced fp32 store ----
  for (int c = t; c < PTS * 192; c += 256){
    int pp = c / 192, r = c % 192;
    ((float4*)(out + (p0 + pp) * 768))[r] = ((const float4*)(Hs + pp * ROWF))[r];
  }
}

// ---------------- launch -----------------------------------------------------
extern "C" void kernel_launch(void* const* d_in, const int* in_sizes, int n_in,
                              void* d_out, int out_size, void* d_ws, size_t ws_size,
                              hipStream_t stream){
  (void)in_sizes; (void)n_in; (void)out_size; (void)ws_size;
  const float* hidden = (const float*)d_in[0];   // [64,1024,48,16] fp32
  const float* refp   = (const float*)d_in[1];   // [64,1,1,16]     fp32
  const float* wbili  = (const float*)d_in[2];   // [96,48,9]       fp32
  const float* wnext  = (const float*)d_in[3];   // [48,48,9]       fp32
  float* outp = (float*)d_out;                   // [64,1024,48,16] fp32

  float* W1 = (float*)d_ws;                 // [9][96][48] fp32 = 165,888 B
  float* W2 = W1 + 9*CH*CIN;                // [9][48][48] fp32 =  82,944 B
                                            // total 248,832 B (known-good)

  prep_weights<<<162, 256, 0, stream>>>(wbili, wnext, W1, W2);
  fused_bilinear<<<NPTS/PTS, 256, 0, stream>>>(hidden, refp, W1, W2, outp);
}